// Round 6
// baseline (20431.619 us; speedup 1.0000x reference)
//
#include <hip/hip_runtime.h>
#include <cstddef>
#include <cstdint>

#define T_LEN 4096
#define FDIM  1024
#define H2DIM 1024
#define GDIM  4096   // 4*H2

#define NEGV (-10000.0f)
#define START_TAG 2
#define STOP_TAG 3

// ---- workspace layout (bytes) ----
#define XP_OFF      ((size_t)0)
#define XP_BYTES    ((size_t)2 * T_LEN * GDIM * 4)          // 134,217,728
#define HIST_OFF    (XP_OFF + XP_BYTES)
#define HIST_BYTES  ((size_t)T_LEN * 2048 * 4)              // 33,554,432
#define FEATS_OFF   (HIST_OFF + HIST_BYTES)
#define FEATS_BYTES ((size_t)T_LEN * 4 * 4)
#define SLOTS_OFF   (FEATS_OFF + FEATS_BYTES)
#define SLOTS_BYTES ((size_t)2 * 2 * 1024 * 8)              // parity x dir x unit, u64
#define WS_NEED     (SLOTS_OFF + SLOTS_BYTES)

__device__ __forceinline__ float sigm(float x) { return 1.0f / (1.0f + expf(-x)); }

typedef unsigned int uintx4 __attribute__((ext_vector_type(4)));

// ============================================================================
// Kernel 1: xp[dir][s][j] = dot(x[row(s)], w_ih_dir[j]) + b_ih[j] + b_hh[j]
// dir=0: row=s ; dir=1: row = 4095-s (backward scan order).
// 128x128 tile, BK=32, 256 threads, 8x8 microtile. fp32 (no fp32 MFMA).
// ============================================================================
__global__ __launch_bounds__(256)
void xp_gemm(const float* __restrict__ x,
             const float* __restrict__ w_f, const float* __restrict__ w_b,
             const float* __restrict__ bi_f, const float* __restrict__ bh_f,
             const float* __restrict__ bi_b, const float* __restrict__ bh_b,
             float* __restrict__ xp)
{
    const int tid = threadIdx.x;
    const int dir = blockIdx.z;
    const int j0  = blockIdx.x * 128;
    const int t0  = blockIdx.y * 128;
    const float* __restrict__ w  = dir ? w_b  : w_f;
    const float* __restrict__ bi = dir ? bi_b : bi_f;
    const float* __restrict__ bh = dir ? bh_b : bh_f;

    __shared__ float As[32][133];   // [k][m], padded
    __shared__ float Bs[32][133];   // [k][n]

    const int tm0 = (tid & 15) * 8;
    const int tn0 = (tid >> 4) * 8;

    float acc[8][8];
    #pragma unroll
    for (int i = 0; i < 8; ++i)
        #pragma unroll
        for (int j = 0; j < 8; ++j) acc[i][j] = 0.f;

    const int lrow = tid >> 3;        // 0..31
    const int lkq  = (tid & 7) * 4;   // 0..28

    for (int kb = 0; kb < FDIM; kb += 32) {
        #pragma unroll
        for (int hh = 0; hh < 4; ++hh) {
            const int r  = lrow + hh * 32;            // 0..127
            const int tg = t0 + r;
            const int sr = dir ? (T_LEN - 1 - tg) : tg;
            const float4 av = *(const float4*)&x[(size_t)sr * FDIM + kb + lkq];
            As[lkq+0][r] = av.x; As[lkq+1][r] = av.y; As[lkq+2][r] = av.z; As[lkq+3][r] = av.w;
            const float4 bv = *(const float4*)&w[(size_t)(j0 + r) * FDIM + kb + lkq];
            Bs[lkq+0][r] = bv.x; Bs[lkq+1][r] = bv.y; Bs[lkq+2][r] = bv.z; Bs[lkq+3][r] = bv.w;
        }
        __syncthreads();
        #pragma unroll
        for (int k = 0; k < 32; ++k) {
            const float4 a0 = *(const float4*)&As[k][tm0];
            const float4 a1 = *(const float4*)&As[k][tm0 + 4];
            const float4 b0 = *(const float4*)&Bs[k][tn0];
            const float4 b1 = *(const float4*)&Bs[k][tn0 + 4];
            const float av[8] = {a0.x,a0.y,a0.z,a0.w,a1.x,a1.y,a1.z,a1.w};
            const float bv[8] = {b0.x,b0.y,b0.z,b0.w,b1.x,b1.y,b1.z,b1.w};
            #pragma unroll
            for (int i = 0; i < 8; ++i)
                #pragma unroll
                for (int j = 0; j < 8; ++j) acc[i][j] += av[i] * bv[j];
        }
        __syncthreads();
    }

    float bias[8];
    #pragma unroll
    for (int j = 0; j < 8; ++j) { const int col = j0 + tn0 + j; bias[j] = bi[col] + bh[col]; }

    float* __restrict__ xpd = xp + (size_t)dir * T_LEN * GDIM;
    #pragma unroll
    for (int i = 0; i < 8; ++i) {
        const int tr = t0 + tm0 + i;
        float4 o0, o1;
        o0.x = acc[i][0] + bias[0]; o0.y = acc[i][1] + bias[1];
        o0.z = acc[i][2] + bias[2]; o0.w = acc[i][3] + bias[3];
        o1.x = acc[i][4] + bias[4]; o1.y = acc[i][5] + bias[5];
        o1.z = acc[i][6] + bias[6]; o1.w = acc[i][7] + bias[7];
        *(float4*)&xpd[(size_t)tr * GDIM + j0 + tn0]     = o0;
        *(float4*)&xpd[(size_t)tr * GDIM + j0 + tn0 + 4] = o1;
    }
}

// ============================================================================
// Kernel 2: cooperative persistent bidirectional LSTM scan, v5.
// 256 blocks x 512 THREADS (8 waves/CU for LDS-latency hiding), 1 block/CU.
// Weights in LDS [32][1032] (pad 8 floats -> per-phase 2-way bank alias, free).
// Wave w owns unit u0+w; thread (g=lane>>4, kc=lane&15) computes a 64-elem
// slice of gate-row g. Reduce: 4 shfl_xor over kc + 3 broadcast shfls -> lane0
// has all 4 gates -> cell inline, single barrier/step, parity-dbuf hbuf.
// Poll: ONE global_load_dwordx4 sc0 sc1 per thread (2 slots, coalesced), no
// sleep -> sweep period ~= LLC latency, low variance. Hang-proof budget kept.
// ============================================================================
#define DOT4(a,b) ((a).x*(b).x + (a).y*(b).y + (a).z*(b).z + (a).w*(b).w)

__global__ __launch_bounds__(512, 1)
void lstm_scan(const float* __restrict__ xp,
               const float* __restrict__ h0,
               const float* __restrict__ c0,
               const float* __restrict__ whh_f,
               const float* __restrict__ whh_b,
               float* __restrict__ hist,
               unsigned long long* __restrict__ slots)
{
    __shared__ float wsl[32][1032];   // 132,096 B (padded rows)
    __shared__ float hbuf[2][1024];   //   8,192 B, parity double-buffer

    const int tid  = threadIdx.x;     // 0..511
    const int b    = blockIdx.x;
    const int dir  = b >> 7;
    const int u0   = (b & 127) * 8;
    const int lane = tid & 63;
    const int wv   = tid >> 6;        // wave index = unit within block, 0..7
    const int g    = lane >> 4;       // gate 0..3
    const int kc   = lane & 15;       // k-chunk 0..15
    const int unit = u0 + wv;
    const int lr   = wv * 4 + g;      // LDS weight row for this thread

    const float* __restrict__ whh = dir ? whh_b : whh_f;
    const size_t xpbase = (size_t)dir * T_LEN * GDIM;

    // ---- stage w_hh slice: LDS row lr = u*4+g  <->  global row (g<<10)+u0+u
    for (int r = 0; r < 32; ++r) {
        const int grow = ((r & 3) << 10) + u0 + (r >> 2);
        *(float2*)&wsl[r][tid * 2] = *(const float2*)&whh[(size_t)grow * H2DIM + tid * 2];
    }

    // ---- init h, c, xp(t=0), xp(t=1) ----
    *(float2*)&hbuf[0][tid * 2] = *(const float2*)&h0[dir * H2DIM + tid * 2];
    float creg = 0.f;
    float xpc0 = 0.f, xpc1 = 0.f, xpc2 = 0.f, xpc3 = 0.f;   // step t
    float xpn0 = 0.f, xpn1 = 0.f, xpn2 = 0.f, xpn3 = 0.f;   // step t+1
    if (lane == 0) {
        creg = c0[dir * H2DIM + unit];
        xpc0 = xp[xpbase + unit];
        xpc1 = xp[xpbase + unit + 1024];
        xpc2 = xp[xpbase + unit + 2048];
        xpc3 = xp[xpbase + unit + 3072];
        xpn0 = xp[xpbase + GDIM + unit];
        xpn1 = xp[xpbase + GDIM + unit + 1024];
        xpn2 = xp[xpbase + GDIM + unit + 2048];
        xpn3 = xp[xpbase + GDIM + unit + 3072];
    }
    __syncthreads();

    int budget = 2000000;   // hang-proof poll budget (sweeps, shared over steps)

    for (int t = 0; t < T_LEN; ++t) {
        const float* __restrict__ hb = hbuf[t & 1];

        // depth-2 prefetch: issue xp(t+2) now, consumed two steps later
        float xq0 = 0.f, xq1 = 0.f, xq2 = 0.f, xq3 = 0.f;
        const int tq = (t + 2 < T_LEN) ? (t + 2) : t;
        if (lane == 0) {
            const size_t base = xpbase + (size_t)tq * GDIM + unit;
            xq0 = xp[base];
            xq1 = xp[base + 1024];
            xq2 = xp[base + 2048];
            xq3 = xp[base + 3072];
        }

        // ---- 64-MAC slice of gate-row lr (weights LDS, h LDS broadcast) ----
        float p = 0.f;
        #pragma unroll
        for (int s = 0; s < 16; ++s) {
            const float4 wvv = *(const float4*)&wsl[lr][s * 64 + kc * 4];
            const float4 hvv = *(const float4*)&hb[s * 64 + kc * 4];
            p += DOT4(wvv, hvv);
        }
        // reduce over the 16 kc lanes (stays within each 16-lane group)
        p += __shfl_xor(p, 1);
        p += __shfl_xor(p, 2);
        p += __shfl_xor(p, 4);
        p += __shfl_xor(p, 8);
        // gate g total now on lane g*16; broadcast to all lanes of the wave
        const float s0 = __shfl(p, 0);
        const float s1 = __shfl(p, 16);
        const float s2 = __shfl(p, 32);
        const float s3 = __shfl(p, 48);

        // ---- cell + publish on lane 0 (one per unit = per wave) ----
        if (lane == 0) {
            const float gi = s0 + xpc0;
            const float gf = s1 + xpc1;
            const float gg = s2 + xpc2;
            const float go = s3 + xpc3;
            const float c  = sigm(gf) * creg + sigm(gi) * tanhf(gg);
            const float h  = sigm(go) * tanhf(c);
            creg = c;
            const int tg = dir ? (T_LEN - 1 - t) : t;
            hist[(size_t)tg * 2048 + dir * H2DIM + unit] = h;
            const unsigned long long pack =
                ((unsigned long long)(unsigned)(t + 1) << 32) |
                (unsigned long long)__float_as_uint(h);
            __hip_atomic_store(&slots[((size_t)((t + 1) & 1) * 2 + dir) * H2DIM + unit],
                               pack, __ATOMIC_RELAXED, __HIP_MEMORY_SCOPE_AGENT);
        }

        // ---- poll 2 slots via one 16B coherent load; write next-parity hbuf
        if (t + 1 < T_LEN) {
            const unsigned want = (unsigned)(t + 1);
            const unsigned long long* sb =
                &slots[((size_t)((t + 1) & 1) * 2 + dir) * H2DIM + tid * 2];
            uintx4 v;
            for (;;) {
                asm volatile("global_load_dwordx4 %0, %1, off sc0 sc1\n\t"
                             "s_waitcnt vmcnt(0)"
                             : "=v"(v) : "v"(sb) : "memory");
                if (v.y == want && v.w == want) break;     // [val0,tag0,val1,tag1]
                if (--budget <= 0) break;                  // hang-proof bail
            }
            float2 hv2;
            hv2.x = __uint_as_float(v.x);
            hv2.y = __uint_as_float(v.z);
            *(float2*)&hbuf[(t + 1) & 1][tid * 2] = hv2;
        }
        __syncthreads();   // next-parity hbuf complete; safe to proceed
        xpc0 = xpn0; xpc1 = xpn1; xpc2 = xpn2; xpc3 = xpn3;
        xpn0 = xq0;  xpn1 = xq1;  xpn2 = xq2;  xpn3 = xq3;
    }
}

// ============================================================================
// Kernel 3: feats[t][n] = dot(hist[t], w_tag[n]) + b_tag[n]
// ============================================================================
__global__ __launch_bounds__(256)
void feats_kernel(const float* __restrict__ hist,
                  const float* __restrict__ w_tag,
                  const float* __restrict__ b_tag,
                  float* __restrict__ feats)
{
    const int t = blockIdx.x;
    const int tid = threadIdx.x;
    const float* __restrict__ hrow = hist + (size_t)t * 2048 + tid * 8;
    const float4 ha = *(const float4*)&hrow[0];
    const float4 hb = *(const float4*)&hrow[4];
    float p[4];
    #pragma unroll
    for (int n = 0; n < 4; ++n) {
        const float* __restrict__ wr = w_tag + n * 2048 + tid * 8;
        const float4 wa = *(const float4*)&wr[0];
        const float4 wb = *(const float4*)&wr[4];
        p[n] = ha.x*wa.x + ha.y*wa.y + ha.z*wa.z + ha.w*wa.w
             + hb.x*wb.x + hb.y*wb.y + hb.z*wb.z + hb.w*wb.w;
    }
    #pragma unroll
    for (int m = 32; m >= 1; m >>= 1) {
        #pragma unroll
        for (int n = 0; n < 4; ++n) p[n] += __shfl_down(p[n], m);
    }
    __shared__ float red[4][4];
    const int wv = tid >> 6;
    if ((tid & 63) == 0) {
        #pragma unroll
        for (int n = 0; n < 4; ++n) red[n][wv] = p[n];
    }
    __syncthreads();
    if (tid < 4)
        feats[(size_t)t * 4 + tid] = red[tid][0] + red[tid][1] + red[tid][2] + red[tid][3] + b_tag[tid];
}

// ============================================================================
// Kernel 4: Viterbi (4 tags): forward DP + backtrace, op-order matches ref.
// ============================================================================
__global__ __launch_bounds__(256)
void viterbi_kernel(const float* __restrict__ feats,
                    const float* __restrict__ trans,
                    float* __restrict__ out)
{
    __shared__ float fsh[T_LEN * 4];   // 64 KB
    __shared__ unsigned bp[T_LEN];     // 16 KB
    const int tid = threadIdx.x;
    for (int i = tid; i < T_LEN; i += 256)
        *(float4*)&fsh[i * 4] = *(const float4*)&feats[(size_t)i * 4];
    __syncthreads();
    if (tid == 0) {
        float tr[16];
        #pragma unroll
        for (int i = 0; i < 16; ++i) tr[i] = trans[i];
        float fv[4] = {NEGV, NEGV, NEGV, NEGV};
        fv[START_TAG] = 0.0f;
        for (int t = 0; t < T_LEN; ++t) {
            float nf[4]; unsigned pb = 0;
            #pragma unroll
            for (int n = 0; n < 4; ++n) {
                float m = fv[0] + tr[n * 4 + 0]; int bsel = 0;
                #pragma unroll
                for (int p = 1; p < 4; ++p) {
                    const float s = fv[p] + tr[n * 4 + p];
                    if (s > m) { m = s; bsel = p; }
                }
                nf[n] = m + fsh[t * 4 + n];
                pb |= (unsigned)bsel << (8 * n);
            }
            bp[t] = pb;
            fv[0] = nf[0]; fv[1] = nf[1]; fv[2] = nf[2]; fv[3] = nf[3];
        }
        float bm = fv[0] + tr[STOP_TAG * 4 + 0]; int best = 0;
        #pragma unroll
        for (int p = 1; p < 4; ++p) {
            const float s = fv[p] + tr[STOP_TAG * 4 + p];
            if (s > bm) { bm = s; best = p; }
        }
        out[0] = bm;
        int cur = best;
        for (int t = T_LEN - 1; t >= 0; --t) {
            out[1 + t] = (float)cur;
            cur = (int)((bp[t] >> (8 * cur)) & 0xffu);
        }
    }
}

// ============================================================================
extern "C" void kernel_launch(void* const* d_in, const int* in_sizes, int n_in,
                              void* d_out, int out_size, void* d_ws, size_t ws_size,
                              hipStream_t stream) {
    const float* x      = (const float*)d_in[0];
    const float* h0     = (const float*)d_in[1];
    const float* c0     = (const float*)d_in[2];
    const float* w_ih_f = (const float*)d_in[3];
    const float* w_hh_f = (const float*)d_in[4];
    const float* b_ih_f = (const float*)d_in[5];
    const float* b_hh_f = (const float*)d_in[6];
    const float* w_ih_b = (const float*)d_in[7];
    const float* w_hh_b = (const float*)d_in[8];
    const float* b_ih_b = (const float*)d_in[9];
    const float* b_hh_b = (const float*)d_in[10];
    const float* w_tag  = (const float*)d_in[11];
    const float* b_tag  = (const float*)d_in[12];
    const float* trans  = (const float*)d_in[13];
    float* out = (float*)d_out;

    if (ws_size < WS_NEED) return;   // signature: output stays poisoned

    char* ws = (char*)d_ws;
    float* xp    = (float*)(ws + XP_OFF);
    float* hist  = (float*)(ws + HIST_OFF);
    float* feats = (float*)(ws + FEATS_OFF);
    unsigned long long* slots = (unsigned long long*)(ws + SLOTS_OFF);

    hipMemsetAsync(slots, 0, SLOTS_BYTES, stream);

    dim3 ggrid(32, 32, 2);
    xp_gemm<<<ggrid, 256, 0, stream>>>(x, w_ih_f, w_ih_b, b_ih_f, b_hh_f, b_ih_b, b_hh_b, xp);

    void* ka[] = { (void*)&xp, (void*)&h0, (void*)&c0, (void*)&w_hh_f, (void*)&w_hh_b,
                   (void*)&hist, (void*)&slots };
    hipLaunchCooperativeKernel((void*)lstm_scan, dim3(256), dim3(512), ka, 0, stream);

    feats_kernel<<<T_LEN, 256, 0, stream>>>(hist, w_tag, b_tag, feats);
    viterbi_kernel<<<1, 256, 0, stream>>>(feats, trans, out);
}

// Round 7
// 18695.764 us; speedup vs baseline: 1.0928x; 1.0928x over previous
//
#include <hip/hip_runtime.h>
#include <cstddef>
#include <cstdint>

#define T_LEN 4096
#define FDIM  1024
#define H2DIM 1024
#define GDIM  4096   // 4*H2

#define NEGV (-10000.0f)
#define START_TAG 2
#define STOP_TAG 3

// ---- workspace layout (bytes) ----
#define XP_OFF      ((size_t)0)
#define XP_BYTES    ((size_t)2 * T_LEN * GDIM * 4)          // 134,217,728
#define HIST_OFF    (XP_OFF + XP_BYTES)
#define HIST_BYTES  ((size_t)T_LEN * 2048 * 4)              // 33,554,432
#define FEATS_OFF   (HIST_OFF + HIST_BYTES)
#define FEATS_BYTES ((size_t)T_LEN * 4 * 4)
#define SLOTS_OFF   (FEATS_OFF + FEATS_BYTES)
#define SLOTS_BYTES ((size_t)2 * 2 * 1024 * 8)              // parity x dir x unit, u64
#define WS_NEED     (SLOTS_OFF + SLOTS_BYTES)

__device__ __forceinline__ float sigm(float x) { return 1.0f / (1.0f + expf(-x)); }

// ============================================================================
// Kernel 1: xp[dir][s][j] = dot(x[row(s)], w_ih_dir[j]) + b_ih[j] + b_hh[j]
// dir=0: row=s ; dir=1: row = 4095-s (backward scan order).
// 128x128 tile, BK=32, 256 threads, 8x8 microtile. fp32 (no fp32 MFMA).
// ============================================================================
__global__ __launch_bounds__(256)
void xp_gemm(const float* __restrict__ x,
             const float* __restrict__ w_f, const float* __restrict__ w_b,
             const float* __restrict__ bi_f, const float* __restrict__ bh_f,
             const float* __restrict__ bi_b, const float* __restrict__ bh_b,
             float* __restrict__ xp)
{
    const int tid = threadIdx.x;
    const int dir = blockIdx.z;
    const int j0  = blockIdx.x * 128;
    const int t0  = blockIdx.y * 128;
    const float* __restrict__ w  = dir ? w_b  : w_f;
    const float* __restrict__ bi = dir ? bi_b : bi_f;
    const float* __restrict__ bh = dir ? bh_b : bh_f;

    __shared__ float As[32][133];   // [k][m], padded
    __shared__ float Bs[32][133];   // [k][n]

    const int tm0 = (tid & 15) * 8;
    const int tn0 = (tid >> 4) * 8;

    float acc[8][8];
    #pragma unroll
    for (int i = 0; i < 8; ++i)
        #pragma unroll
        for (int j = 0; j < 8; ++j) acc[i][j] = 0.f;

    const int lrow = tid >> 3;        // 0..31
    const int lkq  = (tid & 7) * 4;   // 0..28

    for (int kb = 0; kb < FDIM; kb += 32) {
        #pragma unroll
        for (int hh = 0; hh < 4; ++hh) {
            const int r  = lrow + hh * 32;            // 0..127
            const int tg = t0 + r;
            const int sr = dir ? (T_LEN - 1 - tg) : tg;
            const float4 av = *(const float4*)&x[(size_t)sr * FDIM + kb + lkq];
            As[lkq+0][r] = av.x; As[lkq+1][r] = av.y; As[lkq+2][r] = av.z; As[lkq+3][r] = av.w;
            const float4 bv = *(const float4*)&w[(size_t)(j0 + r) * FDIM + kb + lkq];
            Bs[lkq+0][r] = bv.x; Bs[lkq+1][r] = bv.y; Bs[lkq+2][r] = bv.z; Bs[lkq+3][r] = bv.w;
        }
        __syncthreads();
        #pragma unroll
        for (int k = 0; k < 32; ++k) {
            const float4 a0 = *(const float4*)&As[k][tm0];
            const float4 a1 = *(const float4*)&As[k][tm0 + 4];
            const float4 b0 = *(const float4*)&Bs[k][tn0];
            const float4 b1 = *(const float4*)&Bs[k][tn0 + 4];
            const float av[8] = {a0.x,a0.y,a0.z,a0.w,a1.x,a1.y,a1.z,a1.w};
            const float bv[8] = {b0.x,b0.y,b0.z,b0.w,b1.x,b1.y,b1.z,b1.w};
            #pragma unroll
            for (int i = 0; i < 8; ++i)
                #pragma unroll
                for (int j = 0; j < 8; ++j) acc[i][j] += av[i] * bv[j];
        }
        __syncthreads();
    }

    float bias[8];
    #pragma unroll
    for (int j = 0; j < 8; ++j) { const int col = j0 + tn0 + j; bias[j] = bi[col] + bh[col]; }

    float* __restrict__ xpd = xp + (size_t)dir * T_LEN * GDIM;
    #pragma unroll
    for (int i = 0; i < 8; ++i) {
        const int tr = t0 + tm0 + i;
        float4 o0, o1;
        o0.x = acc[i][0] + bias[0]; o0.y = acc[i][1] + bias[1];
        o0.z = acc[i][2] + bias[2]; o0.w = acc[i][3] + bias[3];
        o1.x = acc[i][4] + bias[4]; o1.y = acc[i][5] + bias[5];
        o1.z = acc[i][6] + bias[6]; o1.w = acc[i][7] + bias[7];
        *(float4*)&xpd[(size_t)tr * GDIM + j0 + tn0]     = o0;
        *(float4*)&xpd[(size_t)tr * GDIM + j0 + tn0 + 4] = o1;
    }
}

// ============================================================================
// Kernel 2: cooperative persistent bidirectional LSTM scan, v6.
// 256 blocks x 256 threads, 1 block/CU. Weights in LDS [32][1024] (128 KB) --
// R2's proven conflict-free read pattern (rows lrb..lrb+3, kc-contiguous b128,
// 2 rows/instr at identical bank phase = free 2-way). Rows staged UNIT-major
// (row = rg*4 + g) so the reduction is the R3/R5 value-merging butterfly
// (6 shfl + 3 gather, proven absmax=0) -> cell inline on lane kc==0, ONE
// barrier/step, parity-double-buffered hbuf. Poll = R2-proven atomic loads
// (relaxed, agent scope), no sleep. Slot store issued before hist store.
// ============================================================================
#define DOT4(a,b) ((a).x*(b).x + (a).y*(b).y + (a).z*(b).z + (a).w*(b).w)

__global__ __launch_bounds__(256, 1)
void lstm_scan(const float* __restrict__ xp,
               const float* __restrict__ h0,
               const float* __restrict__ c0,
               const float* __restrict__ whh_f,
               const float* __restrict__ whh_b,
               float* __restrict__ hist,
               unsigned long long* __restrict__ slots)
{
    __shared__ float wsl[32][1024];   // 131,072 B
    __shared__ float hbuf[2][1024];   //   8,192 B, parity double-buffer

    const int tid = threadIdx.x;
    const int b   = blockIdx.x;
    const int dir = b >> 7;
    const int u0  = (b & 127) * 8;
    const int rg  = tid >> 5;   // unit within block: 0..7
    const int kc  = tid & 31;   // k-chunk: float4 at s*128 + kc*4
    const int lrb = rg * 4;     // this thread's 4 weight rows (gates of unit)
    const int unit = u0 + rg;

    const float* __restrict__ whh = dir ? whh_b : whh_f;
    const size_t xpbase = (size_t)dir * T_LEN * GDIM;

    // ---- stage w_hh: LDS row r = rg*4+g  <->  global row (g<<10)+u0+rg ----
    for (int r = 0; r < 32; ++r) {
        const int grow = ((r & 3) << 10) + u0 + (r >> 2);
        *(float4*)&wsl[r][tid * 4] = *(const float4*)&whh[(size_t)grow * H2DIM + tid * 4];
    }

    // ---- init h, c, xp(t=0), xp(t=1) ----
    *(float4*)&hbuf[0][tid * 4] = *(const float4*)&h0[dir * H2DIM + tid * 4];
    float creg = 0.f;
    float xpc0 = 0.f, xpc1 = 0.f, xpc2 = 0.f, xpc3 = 0.f;   // step t
    float xpn0 = 0.f, xpn1 = 0.f, xpn2 = 0.f, xpn3 = 0.f;   // step t+1
    if (kc == 0) {
        creg = c0[dir * H2DIM + unit];
        xpc0 = xp[xpbase + unit];
        xpc1 = xp[xpbase + unit + 1024];
        xpc2 = xp[xpbase + unit + 2048];
        xpc3 = xp[xpbase + unit + 3072];
        xpn0 = xp[xpbase + GDIM + unit];
        xpn1 = xp[xpbase + GDIM + unit + 1024];
        xpn2 = xp[xpbase + GDIM + unit + 2048];
        xpn3 = xp[xpbase + GDIM + unit + 3072];
    }
    __syncthreads();

    int budget = 2000000;   // hang-proof poll budget (sweeps, shared over steps)

    for (int t = 0; t < T_LEN; ++t) {
        const float* __restrict__ hb = hbuf[t & 1];

        // depth-2 prefetch: issue xp(t+2) now, consumed two steps later
        float xq0 = 0.f, xq1 = 0.f, xq2 = 0.f, xq3 = 0.f;
        const int tq = (t + 2 < T_LEN) ? (t + 2) : t;
        if (kc == 0) {
            const size_t base = xpbase + (size_t)tq * GDIM + unit;
            xq0 = xp[base];
            xq1 = xp[base + 1024];
            xq2 = xp[base + 2048];
            xq3 = xp[base + 3072];
        }

        // ---- partial dots: 4 gate rows x 32 k-elems (LDS, conflict-free) ----
        float p0 = 0.f, p1 = 0.f, p2 = 0.f, p3 = 0.f;
        #pragma unroll
        for (int s = 0; s < 8; ++s) {
            const int ko = s * 128 + kc * 4;
            const float4 hv = *(const float4*)&hb[ko];
            const float4 w0 = *(const float4*)&wsl[lrb + 0][ko];
            const float4 w1 = *(const float4*)&wsl[lrb + 1][ko];
            const float4 w2 = *(const float4*)&wsl[lrb + 2][ko];
            const float4 w3 = *(const float4*)&wsl[lrb + 3][ko];
            p0 += DOT4(w0, hv);
            p1 += DOT4(w1, hv);
            p2 += DOT4(w2, hv);
            p3 += DOT4(w3, hv);
        }

        // ---- value-merging butterfly over 32 kc-lanes: 6 shfls ----
        const bool o1 = (kc & 1);
        float sa = o1 ? p0 : p1;
        float ra = __shfl_xor(sa, 1);
        float qa = (o1 ? p1 : p0) + ra;
        float sb = o1 ? p2 : p3;
        float rb = __shfl_xor(sb, 1);
        float qb = (o1 ? p3 : p2) + rb;
        const bool o2 = (kc & 2);
        float sc = o2 ? qa : qb;
        float rc = __shfl_xor(sc, 2);
        float r  = (o2 ? qb : qa) + rc;
        r += __shfl_xor(r, 4);
        r += __shfl_xor(r, 8);
        r += __shfl_xor(r, 16);
        // gather gates 1..3 onto lane kc==0 (3 shfls)
        const float g1 = __shfl_xor(r, 1);
        const float g2 = __shfl_xor(r, 2);
        const float g3 = __shfl_xor(r, 3);

        // ---- cell + publish on lane kc==0 (one per unit) ----
        if (kc == 0) {
            const float gi = r  + xpc0;
            const float gf = g1 + xpc1;
            const float gg = g2 + xpc2;
            const float go = g3 + xpc3;
            const float c  = sigm(gf) * creg + sigm(gi) * tanhf(gg);
            const float h  = sigm(go) * tanhf(c);
            creg = c;
            // publish FIRST (consumers wait on this), hist after
            const unsigned long long pack =
                ((unsigned long long)(unsigned)(t + 1) << 32) |
                (unsigned long long)__float_as_uint(h);
            __hip_atomic_store(&slots[((size_t)((t + 1) & 1) * 2 + dir) * H2DIM + unit],
                               pack, __ATOMIC_RELAXED, __HIP_MEMORY_SCOPE_AGENT);
            const int tg = dir ? (T_LEN - 1 - t) : t;
            hist[(size_t)tg * 2048 + dir * H2DIM + unit] = h;
        }

        // ---- poll peers' h for step t+1; write NEXT-parity hbuf ----
        if (t + 1 < T_LEN) {
            const unsigned want = (unsigned)(t + 1);
            unsigned long long* sb4 = &slots[((size_t)((t + 1) & 1) * 2 + dir) * H2DIM + tid * 4];
            unsigned long long v0 = 0, v1 = 0, v2 = 0, v3 = 0;
            bool d0 = false, d1 = false, d2 = false, d3 = false;
            for (;;) {
                if (!d0) v0 = __hip_atomic_load(&sb4[0], __ATOMIC_RELAXED, __HIP_MEMORY_SCOPE_AGENT);
                if (!d1) v1 = __hip_atomic_load(&sb4[1], __ATOMIC_RELAXED, __HIP_MEMORY_SCOPE_AGENT);
                if (!d2) v2 = __hip_atomic_load(&sb4[2], __ATOMIC_RELAXED, __HIP_MEMORY_SCOPE_AGENT);
                if (!d3) v3 = __hip_atomic_load(&sb4[3], __ATOMIC_RELAXED, __HIP_MEMORY_SCOPE_AGENT);
                d0 = d0 || ((unsigned)(v0 >> 32) == want);
                d1 = d1 || ((unsigned)(v1 >> 32) == want);
                d2 = d2 || ((unsigned)(v2 >> 32) == want);
                d3 = d3 || ((unsigned)(v3 >> 32) == want);
                if (d0 && d1 && d2 && d3) break;
                if (--budget <= 0) break;                // hang-proof bail
            }
            float4 hv;
            hv.x = __uint_as_float((unsigned)v0);
            hv.y = __uint_as_float((unsigned)v1);
            hv.z = __uint_as_float((unsigned)v2);
            hv.w = __uint_as_float((unsigned)v3);
            *(float4*)&hbuf[(t + 1) & 1][tid * 4] = hv;
        }
        __syncthreads();   // next-parity hbuf complete; safe to proceed
        xpc0 = xpn0; xpc1 = xpn1; xpc2 = xpn2; xpc3 = xpn3;
        xpn0 = xq0;  xpn1 = xq1;  xpn2 = xq2;  xpn3 = xq3;
    }
}

// ============================================================================
// Kernel 3: feats[t][n] = dot(hist[t], w_tag[n]) + b_tag[n]
// ============================================================================
__global__ __launch_bounds__(256)
void feats_kernel(const float* __restrict__ hist,
                  const float* __restrict__ w_tag,
                  const float* __restrict__ b_tag,
                  float* __restrict__ feats)
{
    const int t = blockIdx.x;
    const int tid = threadIdx.x;
    const float* __restrict__ hrow = hist + (size_t)t * 2048 + tid * 8;
    const float4 ha = *(const float4*)&hrow[0];
    const float4 hb = *(const float4*)&hrow[4];
    float p[4];
    #pragma unroll
    for (int n = 0; n < 4; ++n) {
        const float* __restrict__ wr = w_tag + n * 2048 + tid * 8;
        const float4 wa = *(const float4*)&wr[0];
        const float4 wb = *(const float4*)&wr[4];
        p[n] = ha.x*wa.x + ha.y*wa.y + ha.z*wa.z + ha.w*wa.w
             + hb.x*wb.x + hb.y*wb.y + hb.z*wb.z + hb.w*wb.w;
    }
    #pragma unroll
    for (int m = 32; m >= 1; m >>= 1) {
        #pragma unroll
        for (int n = 0; n < 4; ++n) p[n] += __shfl_down(p[n], m);
    }
    __shared__ float red[4][4];
    const int wv = tid >> 6;
    if ((tid & 63) == 0) {
        #pragma unroll
        for (int n = 0; n < 4; ++n) red[n][wv] = p[n];
    }
    __syncthreads();
    if (tid < 4)
        feats[(size_t)t * 4 + tid] = red[tid][0] + red[tid][1] + red[tid][2] + red[tid][3] + b_tag[tid];
}

// ============================================================================
// Kernel 4: Viterbi (4 tags): forward DP + backtrace, op-order matches ref.
// ============================================================================
__global__ __launch_bounds__(256)
void viterbi_kernel(const float* __restrict__ feats,
                    const float* __restrict__ trans,
                    float* __restrict__ out)
{
    __shared__ float fsh[T_LEN * 4];   // 64 KB
    __shared__ unsigned bp[T_LEN];     // 16 KB
    const int tid = threadIdx.x;
    for (int i = tid; i < T_LEN; i += 256)
        *(float4*)&fsh[i * 4] = *(const float4*)&feats[(size_t)i * 4];
    __syncthreads();
    if (tid == 0) {
        float tr[16];
        #pragma unroll
        for (int i = 0; i < 16; ++i) tr[i] = trans[i];
        float fv[4] = {NEGV, NEGV, NEGV, NEGV};
        fv[START_TAG] = 0.0f;
        for (int t = 0; t < T_LEN; ++t) {
            float nf[4]; unsigned pb = 0;
            #pragma unroll
            for (int n = 0; n < 4; ++n) {
                float m = fv[0] + tr[n * 4 + 0]; int bsel = 0;
                #pragma unroll
                for (int p = 1; p < 4; ++p) {
                    const float s = fv[p] + tr[n * 4 + p];
                    if (s > m) { m = s; bsel = p; }
                }
                nf[n] = m + fsh[t * 4 + n];
                pb |= (unsigned)bsel << (8 * n);
            }
            bp[t] = pb;
            fv[0] = nf[0]; fv[1] = nf[1]; fv[2] = nf[2]; fv[3] = nf[3];
        }
        float bm = fv[0] + tr[STOP_TAG * 4 + 0]; int best = 0;
        #pragma unroll
        for (int p = 1; p < 4; ++p) {
            const float s = fv[p] + tr[STOP_TAG * 4 + p];
            if (s > bm) { bm = s; best = p; }
        }
        out[0] = bm;
        int cur = best;
        for (int t = T_LEN - 1; t >= 0; --t) {
            out[1 + t] = (float)cur;
            cur = (int)((bp[t] >> (8 * cur)) & 0xffu);
        }
    }
}

// ============================================================================
extern "C" void kernel_launch(void* const* d_in, const int* in_sizes, int n_in,
                              void* d_out, int out_size, void* d_ws, size_t ws_size,
                              hipStream_t stream) {
    const float* x      = (const float*)d_in[0];
    const float* h0     = (const float*)d_in[1];
    const float* c0     = (const float*)d_in[2];
    const float* w_ih_f = (const float*)d_in[3];
    const float* w_hh_f = (const float*)d_in[4];
    const float* b_ih_f = (const float*)d_in[5];
    const float* b_hh_f = (const float*)d_in[6];
    const float* w_ih_b = (const float*)d_in[7];
    const float* w_hh_b = (const float*)d_in[8];
    const float* b_ih_b = (const float*)d_in[9];
    const float* b_hh_b = (const float*)d_in[10];
    const float* w_tag  = (const float*)d_in[11];
    const float* b_tag  = (const float*)d_in[12];
    const float* trans  = (const float*)d_in[13];
    float* out = (float*)d_out;

    if (ws_size < WS_NEED) return;   // signature: output stays poisoned

    char* ws = (char*)d_ws;
    float* xp    = (float*)(ws + XP_OFF);
    float* hist  = (float*)(ws + HIST_OFF);
    float* feats = (float*)(ws + FEATS_OFF);
    unsigned long long* slots = (unsigned long long*)(ws + SLOTS_OFF);

    hipMemsetAsync(slots, 0, SLOTS_BYTES, stream);

    dim3 ggrid(32, 32, 2);
    xp_gemm<<<ggrid, 256, 0, stream>>>(x, w_ih_f, w_ih_b, b_ih_f, b_hh_f, b_ih_b, b_hh_b, xp);

    void* ka[] = { (void*)&xp, (void*)&h0, (void*)&c0, (void*)&w_hh_f, (void*)&w_hh_b,
                   (void*)&hist, (void*)&slots };
    hipLaunchCooperativeKernel((void*)lstm_scan, dim3(256), dim3(256), ka, 0, stream);

    feats_kernel<<<T_LEN, 256, 0, stream>>>(hist, w_tag, b_tag, feats);
    viterbi_kernel<<<1, 256, 0, stream>>>(feats, trans, out);
}